// Round 9
// baseline (400.130 us; speedup 1.0000x reference)
//
#include <hip/hip_runtime.h>
#include <math.h>

#define NCH    1024
#define NN     64
#define CK     32                    // fused-fallback chunk
#define KSC    28.853900817779268f   // 20*log2(e): exp(-cost/0.05) = 2^((sim-1)*KSC)
#define SPLIT  4                     // records per batch in ws
#define WSB    4352                  // floats per record: 4096 gram + 4*64 stats

// stats accumulation from staged registers (nodes 4*(l&15)+k)
#define STAT_Q4(v) { sqp[0]+=(v).x; q2p[0]=fmaf((v).x,(v).x,q2p[0]); \
                     sqp[1]+=(v).y; q2p[1]=fmaf((v).y,(v).y,q2p[1]); \
                     sqp[2]+=(v).z; q2p[2]=fmaf((v).z,(v).z,q2p[2]); \
                     sqp[3]+=(v).w; q2p[3]=fmaf((v).w,(v).w,q2p[3]); }
#define STAT_P4(v) { spp[0]+=(v).x; p2p[0]=fmaf((v).x,(v).x,p2p[0]); \
                     spp[1]+=(v).y; p2p[1]=fmaf((v).y,(v).y,p2p[1]); \
                     spp[2]+=(v).z; p2p[2]=fmaf((v).z,(v).z,p2p[2]); \
                     spp[3]+=(v).w; p2p[3]=fmaf((v).w,(v).w,p2p[3]); }

// ===================== Kernel A: 4x8-tile Gram partials @ 24 waves/CU =====================
// grid = 2048 blocks x 256 thr (4 waves). Block (b,s): channels [s*256,+256).
// Wave w: h=w>>1 picks channel half (128 ch), p=w&1 picks col half (32 cols).
// Each wave stages its own 4-channel chunks in PRIVATE LDS (register prefetch
// one chunk ahead, compiler-managed waits, NO barriers in the main loop).
// Per-lane tile is 4 rows x 8 cols -> acc = 32 VGPR; __launch_bounds__(256,6)
// caps VGPR at ~85 so 6 blocks/CU (24 waves/CU) stay resident vs R3's 16.
__global__ __launch_bounds__(256, 6)
void gram_a48(const float* __restrict__ proto,
              const float* __restrict__ query,
              float* __restrict__ ws)
{
    __shared__ __align__(16) float arena[4096];     // 4 waves x 1024 staging; [64][64] overlay after
    __shared__ float statq[2][2][NN];               // [h][sq|q2][node]
    __shared__ float statp[2][2][NN];               // [h][sp|p2][node]

    const int bid = blockIdx.x;
    const int b = bid >> 2, s = bid & 3;
    const int t = threadIdx.x;
    const int w = t >> 6;            // wave 0..3
    const int l = t & 63;
    const int h = w >> 1;            // channel half 0/1
    const int p = w & 1;             // col half 0/1
    const int r0 = (l & 15) * 4;     // q-node rows owned (4)
    const int cw = (l >> 4) * 8 + p * 32;   // p-node cols owned (8), absolute

    const float* __restrict__ qw = query + (size_t)b * 65536 + (s * 256 + h * 128) * 64;
    const float* __restrict__ pw = proto + (size_t)b * 65536 + (s * 256 + h * 128) * 64;

    float* const stg = &arena[w * 1024];   // private: 2 bufs x 512 floats (q 256 | p 256)

    float acc[4][8];
    #pragma unroll
    for (int i = 0; i < 4; ++i)
        #pragma unroll
        for (int j = 0; j < 8; ++j) acc[i][j] = 0.0f;
    float sqp[4] = {0,0,0,0}, q2p[4] = {0,0,0,0};
    float spp[4] = {0,0,0,0}, p2p[4] = {0,0,0,0};

    // prologue: chunk 0 (4 channels) in registers
    float4 qv = *(const float4*)(qw + 4 * l);
    float4 pv = *(const float4*)(pw + 4 * l);

    #pragma unroll 1
    for (int ch = 0; ch < 32; ++ch) {
        float* const buf = stg + (ch & 1) * 512;
        *(float4*)&buf[4 * l]       = qv;
        *(float4*)&buf[256 + 4 * l] = pv;
        if (p == 0) { STAT_Q4(qv); STAT_P4(pv); }   // wave-uniform; h=0,1 cover disjoint channels

        if (ch + 1 < 32) {                          // register prefetch next chunk
            const float* qn = qw + (ch + 1) * 256;
            const float* pn = pw + (ch + 1) * 256;
            qv = *(const float4*)(qn + 4 * l);
            pv = *(const float4*)(pn + 4 * l);
        }

        #pragma unroll
        for (int cc = 0; cc < 4; ++cc) {
            float4 a  = *(const float4*)&buf[cc * 64 + r0];
            float4 b0 = *(const float4*)&buf[256 + cc * 64 + cw];
            float4 b1 = *(const float4*)&buf[256 + cc * 64 + cw + 4];
            const float av[4] = {a.x, a.y, a.z, a.w};
            const float bv[8] = {b0.x,b0.y,b0.z,b0.w,b1.x,b1.y,b1.z,b1.w};
            #pragma unroll
            for (int i = 0; i < 4; ++i)
                #pragma unroll
                for (int j = 0; j < 8; ++j)
                    acc[i][j] = fmaf(av[i], bv[j], acc[i][j]);
        }
    }

    // ---- stats reduce (valid in p==0 waves): lanes l, l^16, l^32, l^48 cover disjoint channels ----
    #pragma unroll
    for (int k = 0; k < 4; ++k) {
        sqp[k] += __shfl_xor(sqp[k], 16, 64); sqp[k] += __shfl_xor(sqp[k], 32, 64);
        q2p[k] += __shfl_xor(q2p[k], 16, 64); q2p[k] += __shfl_xor(q2p[k], 32, 64);
        spp[k] += __shfl_xor(spp[k], 16, 64); spp[k] += __shfl_xor(spp[k], 32, 64);
        p2p[k] += __shfl_xor(p2p[k], 16, 64); p2p[k] += __shfl_xor(p2p[k], 32, 64);
    }
    if (p == 0 && h == 0 && l < 16) {
        #pragma unroll
        for (int k = 0; k < 4; ++k) {
            statq[0][0][4*l + k] = sqp[k];
            statq[0][1][4*l + k] = q2p[k];
            statp[0][0][4*l + k] = spp[k];
            statp[0][1][4*l + k] = p2p[k];
        }
    }

    __syncthreads();                 // streaming done; arena reusable as [64][64] overlay

    // ---- gram merge: h==0 waves dump (disjoint col halves); h==1 waves add + write record ----
    if (h == 0) {
        #pragma unroll
        for (int i = 0; i < 4; ++i) {
            float4 v0; v0.x=acc[i][0]; v0.y=acc[i][1]; v0.z=acc[i][2]; v0.w=acc[i][3];
            float4 v1; v1.x=acc[i][4]; v1.y=acc[i][5]; v1.z=acc[i][6]; v1.w=acc[i][7];
            *(float4*)&arena[(r0 + i) * 64 + cw]     = v0;
            *(float4*)&arena[(r0 + i) * 64 + cw + 4] = v1;
        }
    }
    __syncthreads();
    if (h == 1) {
        float* __restrict__ wsb = ws + (size_t)bid * WSB;
        #pragma unroll
        for (int i = 0; i < 4; ++i) {
            float4 d0 = *(const float4*)&arena[(r0 + i) * 64 + cw];
            float4 d1 = *(const float4*)&arena[(r0 + i) * 64 + cw + 4];
            d0.x+=acc[i][0]; d0.y+=acc[i][1]; d0.z+=acc[i][2]; d0.w+=acc[i][3];
            d1.x+=acc[i][4]; d1.y+=acc[i][5]; d1.z+=acc[i][6]; d1.w+=acc[i][7];
            *(float4*)&wsb[(r0 + i) * 64 + cw]     = d0;
            *(float4*)&wsb[(r0 + i) * 64 + cw + 4] = d1;
        }
        if (p == 0 && l < 16) {      // wave (h=1,p=0): own stats regs + h=0 partials from LDS
            #pragma unroll
            for (int k = 0; k < 4; ++k) {
                wsb[4096 +   0 + 4*l + k] = statq[0][0][4*l + k] + sqp[k];
                wsb[4096 +  64 + 4*l + k] = statq[0][1][4*l + k] + q2p[k];
                wsb[4096 + 128 + 4*l + k] = statp[0][0][4*l + k] + spp[k];
                wsb[4096 + 192 + 4*l + k] = statp[0][1][4*l + k] + p2p[k];
            }
        }
    }
}

#define DOT16(KK, ARR) ({ \
    float4 x0 = *(const float4*)&ARR[sp4*16 +  0]; \
    float4 x1 = *(const float4*)&ARR[sp4*16 +  4]; \
    float4 x2 = *(const float4*)&ARR[sp4*16 +  8]; \
    float4 x3 = *(const float4*)&ARR[sp4*16 + 12]; \
    float a0 = 0.0f, a1 = 0.0f; \
    a0=fmaf(KK[0],x0.x,a0);  a1=fmaf(KK[1],x0.y,a1); \
    a0=fmaf(KK[2],x0.z,a0);  a1=fmaf(KK[3],x0.w,a1); \
    a0=fmaf(KK[4],x1.x,a0);  a1=fmaf(KK[5],x1.y,a1); \
    a0=fmaf(KK[6],x1.z,a0);  a1=fmaf(KK[7],x1.w,a1); \
    a0=fmaf(KK[8],x2.x,a0);  a1=fmaf(KK[9],x2.y,a1); \
    a0=fmaf(KK[10],x2.z,a0); a1=fmaf(KK[11],x2.w,a1); \
    a0=fmaf(KK[12],x3.x,a0); a1=fmaf(KK[13],x3.y,a1); \
    a0=fmaf(KK[14],x3.z,a0); a1=fmaf(KK[15],x3.w,a1); \
    a0 + a1; })

// ===================== Kernel B: combine + sim + K + Sinkhorn + logits (verified R2/R3) =====================
__global__ __launch_bounds__(256)
void emd_solve(const float* __restrict__ ws, float* __restrict__ out)
{
    __shared__ __align__(16) float stage[16 * 64];
    __shared__ __align__(16) float Kl [NN][68];
    __shared__ __align__(16) float KTl[NN][68];
    __shared__ __align__(16) float statL[4][NN];
    __shared__ __align__(16) float uL[NN];
    __shared__ __align__(16) float vL[NN];
    __shared__ __align__(16) float rL[NN];
    __shared__ __align__(16) float cL[NN];
    __shared__ float redl[4];

    const int b  = blockIdx.x;
    const int t  = threadIdx.x;
    const int tr = t >> 4, tc = t & 15;
    const int n0 = tr * 4, m0 = tc * 4;

    const float* __restrict__ wsb = ws + (size_t)b * SPLIT * WSB;

    float acc[4][4];
    #pragma unroll
    for (int i = 0; i < 4; ++i)
        #pragma unroll
        for (int j = 0; j < 4; ++j) acc[i][j] = 0.0f;
    #pragma unroll
    for (int s = 0; s < SPLIT; ++s) {
        const float* __restrict__ g = wsb + s * WSB;
        #pragma unroll
        for (int i = 0; i < 4; ++i) {
            float4 v = *(const float4*)&g[(n0 + i) * 64 + m0];
            acc[i][0] += v.x; acc[i][1] += v.y; acc[i][2] += v.z; acc[i][3] += v.w;
        }
    }
    if (t < NN) {
        float s0 = 0, s1 = 0, s2 = 0, s3 = 0;
        #pragma unroll
        for (int s = 0; s < SPLIT; ++s) {
            const float* __restrict__ g = wsb + s * WSB + 4096;
            s0 += g[t]; s1 += g[64 + t]; s2 += g[128 + t]; s3 += g[192 + t];
        }
        statL[0][t] = s0; statL[1][t] = s1; statL[2][t] = s2; statL[3][t] = s3;
    }
    #pragma unroll
    for (int i = 0; i < 4; ++i) {
        float s = acc[i][0] + acc[i][1] + acc[i][2] + acc[i][3];
        s += __shfl_xor(s, 1, 64); s += __shfl_xor(s, 2, 64);
        s += __shfl_xor(s, 4, 64); s += __shfl_xor(s, 8, 64);
        if (tc == 0) uL[n0 + i] = s;
    }
    #pragma unroll
    for (int j = 0; j < 4; ++j)
        stage[tr * 64 + m0 + j] = acc[0][j] + acc[1][j] + acc[2][j] + acc[3][j];
    __syncthreads();

    if (t < NN) {
        float cs = 0;
        #pragma unroll
        for (int i = 0; i < 16; ++i) cs += stage[i * 64 + t];
        float w2 = fmaxf(cs * (1.0f/64.0f), 0.0f) + 0.001f;
        float w1 = fmaxf(uL[t] * (1.0f/64.0f), 0.0f) + 0.001f;
        float s1 = w1, s2 = w2;
        #pragma unroll
        for (int m = 1; m < 64; m <<= 1) {
            s1 += __shfl_xor(s1, m, 64);
            s2 += __shfl_xor(s2, m, 64);
        }
        rL[t] = w1 / s1;
        cL[t] = w2 / s2;
        vL[t] = 1.0f;
    }
    {
        float nq_[4], np_[4], sqn[4], spm[4];
        #pragma unroll
        for (int i = 0; i < 4; ++i) {
            float sv  = statL[0][n0 + i];
            float var = statL[1][n0 + i] - sv * sv * (1.0f/1024.0f);
            nq_[i] = fmaxf(sqrtf(fmaxf(var, 0.0f)), 1e-8f);
            sqn[i] = sv;
        }
        #pragma unroll
        for (int j = 0; j < 4; ++j) {
            float sv  = statL[2][m0 + j];
            float var = statL[3][m0 + j] - sv * sv * (1.0f/1024.0f);
            np_[j] = fmaxf(sqrtf(fmaxf(var, 0.0f)), 1e-8f);
            spm[j] = sv;
        }
        #pragma unroll
        for (int i = 0; i < 4; ++i) {
            #pragma unroll
            for (int j = 0; j < 4; ++j) {
                float sim = (acc[i][j] - sqn[i] * spm[j] * (1.0f/1024.0f)) / (nq_[i] * np_[j]);
                acc[i][j] = sim;
                float Kv = exp2f((sim - 1.0f) * KSC);
                Kl [n0 + i][m0 + j] = Kv;
                KTl[m0 + j][n0 + i] = Kv;
            }
        }
    }
    __syncthreads();

    const int sn  = t >> 2;
    const int sp4 = t & 3;
    float Kr[16], KTr[16];
    #pragma unroll
    for (int jj = 0; jj < 4; ++jj) {
        float4 kv = *(const float4*)&Kl [sn][sp4 * 16 + jj * 4];
        float4 kt = *(const float4*)&KTl[sn][sp4 * 16 + jj * 4];
        Kr [jj*4+0]=kv.x; Kr [jj*4+1]=kv.y; Kr [jj*4+2]=kv.z; Kr [jj*4+3]=kv.w;
        KTr[jj*4+0]=kt.x; KTr[jj*4+1]=kt.y; KTr[jj*4+2]=kt.z; KTr[jj*4+3]=kt.w;
    }
    const float rreg = rL[sn];
    const float creg = cL[sn];

    for (int it = 0; it < 100; ++it) {
        float s = DOT16(Kr, vL);
        s += __shfl_xor(s, 1, 64); s += __shfl_xor(s, 2, 64);
        float u = rreg / fmaxf(s, 1e-30f);
        if (sp4 == 0) uL[sn] = u;
        __syncthreads();
        float s2 = DOT16(KTr, uL);
        s2 += __shfl_xor(s2, 1, 64); s2 += __shfl_xor(s2, 2, 64);
        float vv = creg / fmaxf(s2, 1e-30f);
        if (sp4 == 0) vL[sn] = vv;
        __syncthreads();
    }
    {
        float s = DOT16(Kr, vL);
        s += __shfl_xor(s, 1, 64); s += __shfl_xor(s, 2, 64);
        float u = rreg / fmaxf(s, 1e-30f);
        if (sp4 == 0) uL[sn] = u;
    }
    __syncthreads();

    float uu[4], vv_[4];
    #pragma unroll
    for (int i = 0; i < 4; ++i) uu[i]  = uL[n0 + i];
    #pragma unroll
    for (int j = 0; j < 4; ++j) vv_[j] = vL[m0 + j];
    float part = 0.0f;
    #pragma unroll
    for (int i = 0; i < 4; ++i) {
        #pragma unroll
        for (int j = 0; j < 4; ++j) {
            float sim = acc[i][j];
            float Kv  = exp2f((sim - 1.0f) * KSC);
            part = fmaf(sim * Kv, uu[i] * vv_[j], part);
        }
    }
    #pragma unroll
    for (int m = 1; m < 64; m <<= 1) part += __shfl_xor(part, m, 64);
    if ((t & 63) == 0) redl[t >> 6] = part;
    __syncthreads();
    if (t == 0) out[b] = (redl[0] + redl[1] + redl[2] + redl[3]) * (12.5f / 64.0f);
}

// ===================== Fallback: verified fused single-kernel path =====================
#define STAT_QF(v) { sqp[0]+=(v).x; q2p[0]=fmaf((v).x,(v).x,q2p[0]); \
                     sqp[1]+=(v).y; q2p[1]=fmaf((v).y,(v).y,q2p[1]); \
                     sqp[2]+=(v).z; q2p[2]=fmaf((v).z,(v).z,q2p[2]); \
                     sqp[3]+=(v).w; q2p[3]=fmaf((v).w,(v).w,q2p[3]); }
#define STAT_PF(v) { spp[0]+=(v).x; p2p[0]=fmaf((v).x,(v).x,p2p[0]); \
                     spp[1]+=(v).y; p2p[1]=fmaf((v).y,(v).y,p2p[1]); \
                     spp[2]+=(v).z; p2p[2]=fmaf((v).z,(v).z,p2p[2]); \
                     spp[3]+=(v).w; p2p[3]=fmaf((v).w,(v).w,p2p[3]); }

__global__ __launch_bounds__(256)
void deepemd_fused(const float* __restrict__ proto,
                   const float* __restrict__ query,
                   float* __restrict__ out)
{
    __shared__ __align__(16) float stage[2 * CK * NN];
    __shared__ __align__(16) float Kl [NN][68];
    __shared__ __align__(16) float KTl[NN][68];
    __shared__ __align__(16) float statL[4][NN];
    __shared__ __align__(16) float uL[NN];
    __shared__ __align__(16) float vL[NN];
    __shared__ __align__(16) float rL[NN];
    __shared__ __align__(16) float cL[NN];
    __shared__ float redl[4];

    const int b  = blockIdx.x;
    const int t  = threadIdx.x;
    const int tr = t >> 4, tc = t & 15;
    const int n0 = tr * 4, m0 = tc * 4;
    const int ofs = 4 * t;

    const float* __restrict__ pb = proto + (size_t)b * (NCH * NN);
    const float* __restrict__ qb = query + (size_t)b * (NCH * NN);

    float acc[4][4];
    #pragma unroll
    for (int i = 0; i < 4; ++i)
        #pragma unroll
        for (int j = 0; j < 4; ++j) acc[i][j] = 0.0f;
    float sqp[4] = {0,0,0,0}, q2p[4] = {0,0,0,0};
    float spp[4] = {0,0,0,0}, p2p[4] = {0,0,0,0};

    float4 qv0 = *(const float4*)(qb + ofs);
    float4 qv1 = *(const float4*)(qb + 1024 + ofs);
    float4 pv0 = *(const float4*)(pb + ofs);
    float4 pv1 = *(const float4*)(pb + 1024 + ofs);

    for (int ch = 0; ch < NCH / CK; ++ch) {
        if (ch) __syncthreads();
        *(float4*)&stage[       ofs] = qv0;
        *(float4*)&stage[1024 + ofs] = qv1;
        *(float4*)&stage[2048 + ofs] = pv0;
        *(float4*)&stage[3072 + ofs] = pv1;
        float4 nq0, nq1, np0, np1;
        const bool more = (ch + 1 < NCH / CK);
        if (more) {
            const float* qn = qb + (ch + 1) * 2048;
            const float* pn = pb + (ch + 1) * 2048;
            nq0 = *(const float4*)(qn + ofs);
            nq1 = *(const float4*)(qn + 1024 + ofs);
            np0 = *(const float4*)(pn + ofs);
            np1 = *(const float4*)(pn + 1024 + ofs);
        }
        STAT_QF(qv0); STAT_QF(qv1);
        STAT_PF(pv0); STAT_PF(pv1);
        __syncthreads();
        #pragma unroll 8
        for (int cc = 0; cc < CK; ++cc) {
            float4 a  = *(const float4*)&stage[cc * 64 + n0];
            float4 bb = *(const float4*)&stage[2048 + cc * 64 + m0];
            acc[0][0]=fmaf(a.x,bb.x,acc[0][0]); acc[0][1]=fmaf(a.x,bb.y,acc[0][1]);
            acc[0][2]=fmaf(a.x,bb.z,acc[0][2]); acc[0][3]=fmaf(a.x,bb.w,acc[0][3]);
            acc[1][0]=fmaf(a.y,bb.x,acc[1][0]); acc[1][1]=fmaf(a.y,bb.y,acc[1][1]);
            acc[1][2]=fmaf(a.y,bb.z,acc[1][2]); acc[1][3]=fmaf(a.y,bb.w,acc[1][3]);
            acc[2][0]=fmaf(a.z,bb.x,acc[2][0]); acc[2][1]=fmaf(a.z,bb.y,acc[2][1]);
            acc[2][2]=fmaf(a.z,bb.z,acc[2][2]); acc[2][3]=fmaf(a.z,bb.w,acc[2][3]);
            acc[3][0]=fmaf(a.w,bb.x,acc[3][0]); acc[3][1]=fmaf(a.w,bb.y,acc[3][1]);
            acc[3][2]=fmaf(a.w,bb.z,acc[3][2]); acc[3][3]=fmaf(a.w,bb.w,acc[3][3]);
        }
        if (more) { qv0 = nq0; qv1 = nq1; pv0 = np0; pv1 = np1; }
    }
    __syncthreads();

    #pragma unroll
    for (int i = 0; i < 4; ++i) {
        float s = acc[i][0] + acc[i][1] + acc[i][2] + acc[i][3];
        s += __shfl_xor(s, 1, 64); s += __shfl_xor(s, 2, 64);
        s += __shfl_xor(s, 4, 64); s += __shfl_xor(s, 8, 64);
        if (tc == 0) uL[n0 + i] = s;
    }
    #pragma unroll
    for (int k = 0; k < 4; ++k) {
        stage[t*16 +      k] = sqp[k];
        stage[t*16 +  4 + k] = q2p[k];
        stage[t*16 +  8 + k] = spp[k];
        stage[t*16 + 12 + k] = p2p[k];
    }
    __syncthreads();
    if (t < NN) {
        const int g = t >> 2, k = t & 3;
        float ssq = 0, sq2 = 0, ssp = 0, sp2 = 0;
        #pragma unroll
        for (int j = 0; j < 16; ++j) {
            const float* row = &stage[(j * 16 + g) * 16];
            ssq += row[k]; sq2 += row[4 + k]; ssp += row[8 + k]; sp2 += row[12 + k];
        }
        statL[0][t] = ssq; statL[1][t] = sq2; statL[2][t] = ssp; statL[3][t] = sp2;
    }
    __syncthreads();
    #pragma unroll
    for (int j = 0; j < 4; ++j)
        stage[tr * 64 + m0 + j] = acc[0][j] + acc[1][j] + acc[2][j] + acc[3][j];
    __syncthreads();
    if (t < NN) {
        float cs = 0;
        #pragma unroll
        for (int i = 0; i < 16; ++i) cs += stage[i * 64 + t];
        float w2 = fmaxf(cs * (1.0f/64.0f), 0.0f) + 0.001f;
        float w1 = fmaxf(uL[t] * (1.0f/64.0f), 0.0f) + 0.001f;
        float s1 = w1, s2 = w2;
        #pragma unroll
        for (int m = 1; m < 64; m <<= 1) {
            s1 += __shfl_xor(s1, m, 64);
            s2 += __shfl_xor(s2, m, 64);
        }
        rL[t] = w1 / s1;
        cL[t] = w2 / s2;
        vL[t] = 1.0f;
    }
    __syncthreads();

    {
        float nq_[4], np_[4], sqn[4], spm[4];
        #pragma unroll
        for (int i = 0; i < 4; ++i) {
            float sv  = statL[0][n0 + i];
            float var = statL[1][n0 + i] - sv * sv * (1.0f/1024.0f);
            nq_[i] = fmaxf(sqrtf(fmaxf(var, 0.0f)), 1e-8f);
            sqn[i] = sv;
        }
        #pragma unroll
        for (int j = 0; j < 4; ++j) {
            float sv  = statL[2][m0 + j];
            float var = statL[3][m0 + j] - sv * sv * (1.0f/1024.0f);
            np_[j] = fmaxf(sqrtf(fmaxf(var, 0.0f)), 1e-8f);
            spm[j] = sv;
        }
        #pragma unroll
        for (int i = 0; i < 4; ++i) {
            #pragma unroll
            for (int j = 0; j < 4; ++j) {
                float sim = (acc[i][j] - sqn[i] * spm[j] * (1.0f/1024.0f)) / (nq_[i] * np_[j]);
                acc[i][j] = sim;
                float Kv = exp2f((sim - 1.0f) * KSC);
                Kl [n0 + i][m0 + j] = Kv;
                KTl[m0 + j][n0 + i] = Kv;
            }
        }
    }
    __syncthreads();

    const int sn  = t >> 2;
    const int sp4 = t & 3;
    float Kr[16], KTr[16];
    #pragma unroll
    for (int jj = 0; jj < 4; ++jj) {
        float4 kv = *(const float4*)&Kl [sn][sp4 * 16 + jj * 4];
        float4 kt = *(const float4*)&KTl[sn][sp4 * 16 + jj * 4];
        Kr [jj*4+0]=kv.x; Kr [jj*4+1]=kv.y; Kr [jj*4+2]=kv.z; Kr [jj*4+3]=kv.w;
        KTr[jj*4+0]=kt.x; KTr[jj*4+1]=kt.y; KTr[jj*4+2]=kt.z; KTr[jj*4+3]=kt.w;
    }
    const float rreg = rL[sn];
    const float creg = cL[sn];

    for (int it = 0; it < 100; ++it) {
        float s = DOT16(Kr, vL);
        s += __shfl_xor(s, 1, 64); s += __shfl_xor(s, 2, 64);
        float u = rreg / fmaxf(s, 1e-30f);
        if (sp4 == 0) uL[sn] = u;
        __syncthreads();
        float s2 = DOT16(KTr, uL);
        s2 += __shfl_xor(s2, 1, 64); s2 += __shfl_xor(s2, 2, 64);
        float vv = creg / fmaxf(s2, 1e-30f);
        if (sp4 == 0) vL[sn] = vv;
        __syncthreads();
    }
    {
        float s = DOT16(Kr, vL);
        s += __shfl_xor(s, 1, 64); s += __shfl_xor(s, 2, 64);
        float u = rreg / fmaxf(s, 1e-30f);
        if (sp4 == 0) uL[sn] = u;
    }
    __syncthreads();

    float uu[4], vv_[4];
    #pragma unroll
    for (int i = 0; i < 4; ++i) uu[i]  = uL[n0 + i];
    #pragma unroll
    for (int j = 0; j < 4; ++j) vv_[j] = vL[m0 + j];
    float part = 0.0f;
    #pragma unroll
    for (int i = 0; i < 4; ++i) {
        #pragma unroll
        for (int j = 0; j < 4; ++j) {
            float sim = acc[i][j];
            float Kv  = exp2f((sim - 1.0f) * KSC);
            part = fmaf(sim * Kv, uu[i] * vv_[j], part);
        }
    }
    #pragma unroll
    for (int m = 1; m < 64; m <<= 1) part += __shfl_xor(part, m, 64);
    if ((t & 63) == 0) redl[t >> 6] = part;
    __syncthreads();
    if (t == 0) out[b] = (redl[0] + redl[1] + redl[2] + redl[3]) * (12.5f / 64.0f);
}

extern "C" void kernel_launch(void* const* d_in, const int* in_sizes, int n_in,
                              void* d_out, int out_size, void* d_ws, size_t ws_size,
                              hipStream_t stream) {
    const float* proto = (const float*)d_in[0];
    const float* query = (const float*)d_in[1];
    float* out = (float*)d_out;
    (void)in_sizes; (void)n_in; (void)out_size;

    const size_t need = (size_t)512 * SPLIT * WSB * sizeof(float);   // ~35.7 MB
    if (ws_size >= need) {
        gram_a48 <<<dim3(512 * SPLIT), dim3(256), 0, stream>>>(proto, query, (float*)d_ws);
        emd_solve<<<dim3(512),         dim3(256), 0, stream>>>((const float*)d_ws, out);
    } else {
        deepemd_fused<<<dim3(512), dim3(256), 0, stream>>>(proto, query, out);
    }
}

// Round 10
// 135.477 us; speedup vs baseline: 2.9535x; 2.9535x over previous
//
#include <hip/hip_runtime.h>
#include <math.h>

#define NCH    1024
#define NN     64
#define CK     32                    // fused-fallback chunk
#define KSC    28.853900817779268f   // 20*log2(e): exp(-cost/0.05) = 2^((sim-1)*KSC)
#define SPLIT  4                     // records per batch in ws
#define WSB    4352                  // floats per record: 4096 gram + 4*64 stats

// stats accumulation from staged registers (nodes 4*(l&15)+k of channel l>>4)
#define STAT_Q(v) { sqp[0]+=(v).x; q2p[0]=fmaf((v).x,(v).x,q2p[0]); \
                    sqp[1]+=(v).y; q2p[1]=fmaf((v).y,(v).y,q2p[1]); \
                    sqp[2]+=(v).z; q2p[2]=fmaf((v).z,(v).z,q2p[2]); \
                    sqp[3]+=(v).w; q2p[3]=fmaf((v).w,(v).w,q2p[3]); }
#define STAT_P(v) { spp[0]+=(v).x; p2p[0]=fmaf((v).x,(v).x,p2p[0]); \
                    spp[1]+=(v).y; p2p[1]=fmaf((v).y,(v).y,p2p[1]); \
                    spp[2]+=(v).z; p2p[2]=fmaf((v).z,(v).z,p2p[2]); \
                    spp[3]+=(v).w; p2p[3]=fmaf((v).w,(v).w,p2p[3]); }

// ===================== Kernel A: 4-wave read-first Gram partials =====================
// grid = 2048 blocks x 256 thr (4 waves). Block (b,s): channels [s*256,+256);
// wave w owns [.. + w*64, +64) in 16 chunks of 4 channels. Wave-private LDS
// double buffer (compile-time offsets via 2x manual unroll); per iteration:
// COMPUTE(chunk k) issues reads FIRST, then stores chunk k+1 into the OTHER
// buffer, then prefetches chunk k+2 from global. No barriers until the merge.
__global__ __launch_bounds__(256)
void gram_w4(const float* __restrict__ proto,
             const float* __restrict__ query,
             float* __restrict__ ws)
{
    __shared__ __align__(16) float arena[4096];   // 4 waves x 1024 staging; [64][64] overlay after
    __shared__ float st[4][4][NN];                // [sq|q2|sp|p2][wave][node]

    const int bid = blockIdx.x;
    const int b = bid >> 2, s = bid & 3;
    const int t = threadIdx.x;
    const int w = t >> 6;            // wave 0..3
    const int l = t & 63;
    const int r0 = (l >> 3) * 8;     // q-node rows owned (8)
    const int c0 = (l & 7) * 8;      // p-node cols owned (8)

    const float* __restrict__ qw = query + (size_t)b * 65536 + (s * 256 + w * 64) * 64;
    const float* __restrict__ pw = proto + (size_t)b * 65536 + (s * 256 + w * 64) * 64;

    float* const stg = &arena[w * 1024];   // bufA at +0 (q 256 | p 256), bufB at +512

    float acc[8][8];
    #pragma unroll
    for (int i = 0; i < 8; ++i)
        #pragma unroll
        for (int j = 0; j < 8; ++j) acc[i][j] = 0.0f;
    float sqp[4] = {0,0,0,0}, q2p[4] = {0,0,0,0};
    float spp[4] = {0,0,0,0}, p2p[4] = {0,0,0,0};

#define COMPUTE(OFF) do {                                                    \
        _Pragma("unroll")                                                    \
        for (int cc = 0; cc < 4; ++cc) {                                     \
            float4 a0 = *(const float4*)&stg[(OFF) + cc * 64 + r0];          \
            float4 a1 = *(const float4*)&stg[(OFF) + cc * 64 + r0 + 4];      \
            float4 b0 = *(const float4*)&stg[(OFF) + 256 + cc * 64 + c0];    \
            float4 b1 = *(const float4*)&stg[(OFF) + 256 + cc * 64 + c0 + 4];\
            const float av[8] = {a0.x,a0.y,a0.z,a0.w,a1.x,a1.y,a1.z,a1.w};   \
            const float bv[8] = {b0.x,b0.y,b0.z,b0.w,b1.x,b1.y,b1.z,b1.w};   \
            _Pragma("unroll")                                                \
            for (int i = 0; i < 8; ++i)                                      \
                _Pragma("unroll")                                            \
                for (int j = 0; j < 8; ++j)                                  \
                    acc[i][j] = fmaf(av[i], bv[j], acc[i][j]);               \
        }                                                                    \
    } while (0)

#define STORE(OFF) do {                                  \
        *(float4*)&stg[(OFF) + 4 * l]       = qv;        \
        *(float4*)&stg[(OFF) + 256 + 4 * l] = pv;        \
    } while (0)

#define PREFETCH(CH) do {                                \
        qv = *(const float4*)(qw + (CH) * 256 + 4 * l);  \
        pv = *(const float4*)(pw + (CH) * 256 + 4 * l);  \
    } while (0)

    // prologue: stage chunk 0 into bufA; regs hold chunk 1
    float4 qv, pv;
    PREFETCH(0);
    STAT_Q(qv); STAT_P(pv);
    STORE(0);
    PREFETCH(1);

    #pragma unroll 1
    for (int ch = 0; ch < 16; ch += 2) {
        // even phase: compute bufA (chunk ch); store chunk ch+1 -> bufB
        COMPUTE(0);
        STAT_Q(qv); STAT_P(pv);
        STORE(512);
        if (ch + 2 < 16) PREFETCH(ch + 2);
        // odd phase: compute bufB (chunk ch+1); store chunk ch+2 -> bufA
        COMPUTE(512);
        if (ch + 2 < 16) {
            STAT_Q(qv); STAT_P(pv);
            STORE(0);
            if (ch + 3 < 16) PREFETCH(ch + 3);
        }
    }
#undef COMPUTE
#undef STORE
#undef PREFETCH

    // ---- stats reduce: lanes l, l^16, l^32, l^48 cover disjoint channels of nodes 4*(l&15)+k ----
    #pragma unroll
    for (int k = 0; k < 4; ++k) {
        sqp[k] += __shfl_xor(sqp[k], 16, 64); sqp[k] += __shfl_xor(sqp[k], 32, 64);
        q2p[k] += __shfl_xor(q2p[k], 16, 64); q2p[k] += __shfl_xor(q2p[k], 32, 64);
        spp[k] += __shfl_xor(spp[k], 16, 64); spp[k] += __shfl_xor(spp[k], 32, 64);
        p2p[k] += __shfl_xor(p2p[k], 16, 64); p2p[k] += __shfl_xor(p2p[k], 32, 64);
    }
    if (l < 16) {
        #pragma unroll
        for (int k = 0; k < 4; ++k) {
            st[0][w][4*l + k] = sqp[k];
            st[1][w][4*l + k] = q2p[k];
            st[2][w][4*l + k] = spp[k];
            st[3][w][4*l + k] = p2p[k];
        }
    }
    __syncthreads();                 // staging dead; arena reusable as [64][64]

    // ---- serialized 4-wave gram merge ----
    if (w == 0) {
        #pragma unroll
        for (int i = 0; i < 8; ++i) {
            float4 v0; v0.x=acc[i][0]; v0.y=acc[i][1]; v0.z=acc[i][2]; v0.w=acc[i][3];
            float4 v1; v1.x=acc[i][4]; v1.y=acc[i][5]; v1.z=acc[i][6]; v1.w=acc[i][7];
            *(float4*)&arena[(r0 + i) * 64 + c0]     = v0;
            *(float4*)&arena[(r0 + i) * 64 + c0 + 4] = v1;
        }
    }
    __syncthreads();
    if (w == 1) {
        #pragma unroll
        for (int i = 0; i < 8; ++i) {
            float* g0 = &arena[(r0 + i) * 64 + c0];
            float* g1 = &arena[(r0 + i) * 64 + c0 + 4];
            float4 d0 = *(const float4*)g0;
            float4 d1 = *(const float4*)g1;
            d0.x+=acc[i][0]; d0.y+=acc[i][1]; d0.z+=acc[i][2]; d0.w+=acc[i][3];
            d1.x+=acc[i][4]; d1.y+=acc[i][5]; d1.z+=acc[i][6]; d1.w+=acc[i][7];
            *(float4*)g0 = d0;
            *(float4*)g1 = d1;
        }
    }
    __syncthreads();
    if (w == 2) {
        #pragma unroll
        for (int i = 0; i < 8; ++i) {
            float* g0 = &arena[(r0 + i) * 64 + c0];
            float* g1 = &arena[(r0 + i) * 64 + c0 + 4];
            float4 d0 = *(const float4*)g0;
            float4 d1 = *(const float4*)g1;
            d0.x+=acc[i][0]; d0.y+=acc[i][1]; d0.z+=acc[i][2]; d0.w+=acc[i][3];
            d1.x+=acc[i][4]; d1.y+=acc[i][5]; d1.z+=acc[i][6]; d1.w+=acc[i][7];
            *(float4*)g0 = d0;
            *(float4*)g1 = d1;
        }
    }
    __syncthreads();
    if (w == 3) {
        float* __restrict__ wsb = ws + (size_t)bid * WSB;
        #pragma unroll
        for (int i = 0; i < 8; ++i) {
            float4 d0 = *(const float4*)&arena[(r0 + i) * 64 + c0];
            float4 d1 = *(const float4*)&arena[(r0 + i) * 64 + c0 + 4];
            d0.x+=acc[i][0]; d0.y+=acc[i][1]; d0.z+=acc[i][2]; d0.w+=acc[i][3];
            d1.x+=acc[i][4]; d1.y+=acc[i][5]; d1.z+=acc[i][6]; d1.w+=acc[i][7];
            *(float4*)&wsb[(r0 + i) * 64 + c0]     = d0;
            *(float4*)&wsb[(r0 + i) * 64 + c0 + 4] = d1;
        }
        #pragma unroll
        for (int k = 0; k < 4; ++k)
            wsb[4096 + k * 64 + l] = st[k][0][l] + st[k][1][l] + st[k][2][l] + st[k][3][l];
    }
}

#define DOT16(KK, ARR) ({ \
    float4 x0 = *(const float4*)&ARR[sp4*16 +  0]; \
    float4 x1 = *(const float4*)&ARR[sp4*16 +  4]; \
    float4 x2 = *(const float4*)&ARR[sp4*16 +  8]; \
    float4 x3 = *(const float4*)&ARR[sp4*16 + 12]; \
    float a0 = 0.0f, a1 = 0.0f; \
    a0=fmaf(KK[0],x0.x,a0);  a1=fmaf(KK[1],x0.y,a1); \
    a0=fmaf(KK[2],x0.z,a0);  a1=fmaf(KK[3],x0.w,a1); \
    a0=fmaf(KK[4],x1.x,a0);  a1=fmaf(KK[5],x1.y,a1); \
    a0=fmaf(KK[6],x1.z,a0);  a1=fmaf(KK[7],x1.w,a1); \
    a0=fmaf(KK[8],x2.x,a0);  a1=fmaf(KK[9],x2.y,a1); \
    a0=fmaf(KK[10],x2.z,a0); a1=fmaf(KK[11],x2.w,a1); \
    a0=fmaf(KK[12],x3.x,a0); a1=fmaf(KK[13],x3.y,a1); \
    a0=fmaf(KK[14],x3.z,a0); a1=fmaf(KK[15],x3.w,a1); \
    a0 + a1; })

// ===================== Kernel B: combine + sim + K + Sinkhorn + logits (verified R2/R3) =====================
__global__ __launch_bounds__(256)
void emd_solve(const float* __restrict__ ws, float* __restrict__ out)
{
    __shared__ __align__(16) float stage[16 * 64];
    __shared__ __align__(16) float Kl [NN][68];
    __shared__ __align__(16) float KTl[NN][68];
    __shared__ __align__(16) float statL[4][NN];
    __shared__ __align__(16) float uL[NN];
    __shared__ __align__(16) float vL[NN];
    __shared__ __align__(16) float rL[NN];
    __shared__ __align__(16) float cL[NN];
    __shared__ float redl[4];

    const int b  = blockIdx.x;
    const int t  = threadIdx.x;
    const int tr = t >> 4, tc = t & 15;
    const int n0 = tr * 4, m0 = tc * 4;

    const float* __restrict__ wsb = ws + (size_t)b * SPLIT * WSB;

    float acc[4][4];
    #pragma unroll
    for (int i = 0; i < 4; ++i)
        #pragma unroll
        for (int j = 0; j < 4; ++j) acc[i][j] = 0.0f;
    #pragma unroll
    for (int s = 0; s < SPLIT; ++s) {
        const float* __restrict__ g = wsb + s * WSB;
        #pragma unroll
        for (int i = 0; i < 4; ++i) {
            float4 v = *(const float4*)&g[(n0 + i) * 64 + m0];
            acc[i][0] += v.x; acc[i][1] += v.y; acc[i][2] += v.z; acc[i][3] += v.w;
        }
    }
    if (t < NN) {
        float s0 = 0, s1 = 0, s2 = 0, s3 = 0;
        #pragma unroll
        for (int s = 0; s < SPLIT; ++s) {
            const float* __restrict__ g = wsb + s * WSB + 4096;
            s0 += g[t]; s1 += g[64 + t]; s2 += g[128 + t]; s3 += g[192 + t];
        }
        statL[0][t] = s0; statL[1][t] = s1; statL[2][t] = s2; statL[3][t] = s3;
    }
    #pragma unroll
    for (int i = 0; i < 4; ++i) {
        float s = acc[i][0] + acc[i][1] + acc[i][2] + acc[i][3];
        s += __shfl_xor(s, 1, 64); s += __shfl_xor(s, 2, 64);
        s += __shfl_xor(s, 4, 64); s += __shfl_xor(s, 8, 64);
        if (tc == 0) uL[n0 + i] = s;
    }
    #pragma unroll
    for (int j = 0; j < 4; ++j)
        stage[tr * 64 + m0 + j] = acc[0][j] + acc[1][j] + acc[2][j] + acc[3][j];
    __syncthreads();

    if (t < NN) {
        float cs = 0;
        #pragma unroll
        for (int i = 0; i < 16; ++i) cs += stage[i * 64 + t];
        float w2 = fmaxf(cs * (1.0f/64.0f), 0.0f) + 0.001f;
        float w1 = fmaxf(uL[t] * (1.0f/64.0f), 0.0f) + 0.001f;
        float s1 = w1, s2 = w2;
        #pragma unroll
        for (int m = 1; m < 64; m <<= 1) {
            s1 += __shfl_xor(s1, m, 64);
            s2 += __shfl_xor(s2, m, 64);
        }
        rL[t] = w1 / s1;
        cL[t] = w2 / s2;
        vL[t] = 1.0f;
    }
    {
        float nq_[4], np_[4], sqn[4], spm[4];
        #pragma unroll
        for (int i = 0; i < 4; ++i) {
            float sv  = statL[0][n0 + i];
            float var = statL[1][n0 + i] - sv * sv * (1.0f/1024.0f);
            nq_[i] = fmaxf(sqrtf(fmaxf(var, 0.0f)), 1e-8f);
            sqn[i] = sv;
        }
        #pragma unroll
        for (int j = 0; j < 4; ++j) {
            float sv  = statL[2][m0 + j];
            float var = statL[3][m0 + j] - sv * sv * (1.0f/1024.0f);
            np_[j] = fmaxf(sqrtf(fmaxf(var, 0.0f)), 1e-8f);
            spm[j] = sv;
        }
        #pragma unroll
        for (int i = 0; i < 4; ++i) {
            #pragma unroll
            for (int j = 0; j < 4; ++j) {
                float sim = (acc[i][j] - sqn[i] * spm[j] * (1.0f/1024.0f)) / (nq_[i] * np_[j]);
                acc[i][j] = sim;
                float Kv = exp2f((sim - 1.0f) * KSC);
                Kl [n0 + i][m0 + j] = Kv;
                KTl[m0 + j][n0 + i] = Kv;
            }
        }
    }
    __syncthreads();

    const int sn  = t >> 2;
    const int sp4 = t & 3;
    float Kr[16], KTr[16];
    #pragma unroll
    for (int jj = 0; jj < 4; ++jj) {
        float4 kv = *(const float4*)&Kl [sn][sp4 * 16 + jj * 4];
        float4 kt = *(const float4*)&KTl[sn][sp4 * 16 + jj * 4];
        Kr [jj*4+0]=kv.x; Kr [jj*4+1]=kv.y; Kr [jj*4+2]=kv.z; Kr [jj*4+3]=kv.w;
        KTr[jj*4+0]=kt.x; KTr[jj*4+1]=kt.y; KTr[jj*4+2]=kt.z; KTr[jj*4+3]=kt.w;
    }
    const float rreg = rL[sn];
    const float creg = cL[sn];

    for (int it = 0; it < 100; ++it) {
        float s = DOT16(Kr, vL);
        s += __shfl_xor(s, 1, 64); s += __shfl_xor(s, 2, 64);
        float u = rreg / fmaxf(s, 1e-30f);
        if (sp4 == 0) uL[sn] = u;
        __syncthreads();
        float s2 = DOT16(KTr, uL);
        s2 += __shfl_xor(s2, 1, 64); s2 += __shfl_xor(s2, 2, 64);
        float vv = creg / fmaxf(s2, 1e-30f);
        if (sp4 == 0) vL[sn] = vv;
        __syncthreads();
    }
    {
        float s = DOT16(Kr, vL);
        s += __shfl_xor(s, 1, 64); s += __shfl_xor(s, 2, 64);
        float u = rreg / fmaxf(s, 1e-30f);
        if (sp4 == 0) uL[sn] = u;
    }
    __syncthreads();

    float uu[4], vv_[4];
    #pragma unroll
    for (int i = 0; i < 4; ++i) uu[i]  = uL[n0 + i];
    #pragma unroll
    for (int j = 0; j < 4; ++j) vv_[j] = vL[m0 + j];
    float part = 0.0f;
    #pragma unroll
    for (int i = 0; i < 4; ++i) {
        #pragma unroll
        for (int j = 0; j < 4; ++j) {
            float sim = acc[i][j];
            float Kv  = exp2f((sim - 1.0f) * KSC);
            part = fmaf(sim * Kv, uu[i] * vv_[j], part);
        }
    }
    #pragma unroll
    for (int m = 1; m < 64; m <<= 1) part += __shfl_xor(part, m, 64);
    if ((t & 63) == 0) redl[t >> 6] = part;
    __syncthreads();
    if (t == 0) out[b] = (redl[0] + redl[1] + redl[2] + redl[3]) * (12.5f / 64.0f);
}

// ===================== Fallback: verified fused single-kernel path =====================
#define STAT_QF(v) { sqp[0]+=(v).x; q2p[0]=fmaf((v).x,(v).x,q2p[0]); \
                     sqp[1]+=(v).y; q2p[1]=fmaf((v).y,(v).y,q2p[1]); \
                     sqp[2]+=(v).z; q2p[2]=fmaf((v).z,(v).z,q2p[2]); \
                     sqp[3]+=(v).w; q2p[3]=fmaf((v).w,(v).w,q2p[3]); }
#define STAT_PF(v) { spp[0]+=(v).x; p2p[0]=fmaf((v).x,(v).x,p2p[0]); \
                     spp[1]+=(v).y; p2p[1]=fmaf((v).y,(v).y,p2p[1]); \
                     spp[2]+=(v).z; p2p[2]=fmaf((v).z,(v).z,p2p[2]); \
                     spp[3]+=(v).w; p2p[3]=fmaf((v).w,(v).w,p2p[3]); }

__global__ __launch_bounds__(256)
void deepemd_fused(const float* __restrict__ proto,
                   const float* __restrict__ query,
                   float* __restrict__ out)
{
    __shared__ __align__(16) float stage[2 * CK * NN];
    __shared__ __align__(16) float Kl [NN][68];
    __shared__ __align__(16) float KTl[NN][68];
    __shared__ __align__(16) float statL[4][NN];
    __shared__ __align__(16) float uL[NN];
    __shared__ __align__(16) float vL[NN];
    __shared__ __align__(16) float rL[NN];
    __shared__ __align__(16) float cL[NN];
    __shared__ float redl[4];

    const int b  = blockIdx.x;
    const int t  = threadIdx.x;
    const int tr = t >> 4, tc = t & 15;
    const int n0 = tr * 4, m0 = tc * 4;
    const int ofs = 4 * t;

    const float* __restrict__ pb = proto + (size_t)b * (NCH * NN);
    const float* __restrict__ qb = query + (size_t)b * (NCH * NN);

    float acc[4][4];
    #pragma unroll
    for (int i = 0; i < 4; ++i)
        #pragma unroll
        for (int j = 0; j < 4; ++j) acc[i][j] = 0.0f;
    float sqp[4] = {0,0,0,0}, q2p[4] = {0,0,0,0};
    float spp[4] = {0,0,0,0}, p2p[4] = {0,0,0,0};

    float4 qv0 = *(const float4*)(qb + ofs);
    float4 qv1 = *(const float4*)(qb + 1024 + ofs);
    float4 pv0 = *(const float4*)(pb + ofs);
    float4 pv1 = *(const float4*)(pb + 1024 + ofs);

    for (int ch = 0; ch < NCH / CK; ++ch) {
        if (ch) __syncthreads();
        *(float4*)&stage[       ofs] = qv0;
        *(float4*)&stage[1024 + ofs] = qv1;
        *(float4*)&stage[2048 + ofs] = pv0;
        *(float4*)&stage[3072 + ofs] = pv1;
        float4 nq0, nq1, np0, np1;
        const bool more = (ch + 1 < NCH / CK);
        if (more) {
            const float* qn = qb + (ch + 1) * 2048;
            const float* pn = pb + (ch + 1) * 2048;
            nq0 = *(const float4*)(qn + ofs);
            nq1 = *(const float4*)(qn + 1024 + ofs);
            np0 = *(const float4*)(pn + ofs);
            np1 = *(const float4*)(pn + 1024 + ofs);
        }
        STAT_QF(qv0); STAT_QF(qv1);
        STAT_PF(pv0); STAT_PF(pv1);
        __syncthreads();
        #pragma unroll 8
        for (int cc = 0; cc < CK; ++cc) {
            float4 a  = *(const float4*)&stage[cc * 64 + n0];
            float4 bb = *(const float4*)&stage[2048 + cc * 64 + m0];
            acc[0][0]=fmaf(a.x,bb.x,acc[0][0]); acc[0][1]=fmaf(a.x,bb.y,acc[0][1]);
            acc[0][2]=fmaf(a.x,bb.z,acc[0][2]); acc[0][3]=fmaf(a.x,bb.w,acc[0][3]);
            acc[1][0]=fmaf(a.y,bb.x,acc[1][0]); acc[1][1]=fmaf(a.y,bb.y,acc[1][1]);
            acc[1][2]=fmaf(a.y,bb.z,acc[1][2]); acc[1][3]=fmaf(a.y,bb.w,acc[1][3]);
            acc[2][0]=fmaf(a.z,bb.x,acc[2][0]); acc[2][1]=fmaf(a.z,bb.y,acc[2][1]);
            acc[2][2]=fmaf(a.z,bb.z,acc[2][2]); acc[2][3]=fmaf(a.z,bb.w,acc[2][3]);
            acc[3][0]=fmaf(a.w,bb.x,acc[3][0]); acc[3][1]=fmaf(a.w,bb.y,acc[3][1]);
            acc[3][2]=fmaf(a.w,bb.z,acc[3][2]); acc[3][3]=fmaf(a.w,bb.w,acc[3][3]);
        }
        if (more) { qv0 = nq0; qv1 = nq1; pv0 = np0; pv1 = np1; }
    }
    __syncthreads();

    #pragma unroll
    for (int i = 0; i < 4; ++i) {
        float s = acc[i][0] + acc[i][1] + acc[i][2] + acc[i][3];
        s += __shfl_xor(s, 1, 64); s += __shfl_xor(s, 2, 64);
        s += __shfl_xor(s, 4, 64); s += __shfl_xor(s, 8, 64);
        if (tc == 0) uL[n0 + i] = s;
    }
    #pragma unroll
    for (int k = 0; k < 4; ++k) {
        stage[t*16 +      k] = sqp[k];
        stage[t*16 +  4 + k] = q2p[k];
        stage[t*16 +  8 + k] = spp[k];
        stage[t*16 + 12 + k] = p2p[k];
    }
    __syncthreads();
    if (t < NN) {
        const int g = t >> 2, k = t & 3;
        float ssq = 0, sq2 = 0, ssp = 0, sp2 = 0;
        #pragma unroll
        for (int j = 0; j < 16; ++j) {
            const float* row = &stage[(j * 16 + g) * 16];
            ssq += row[k]; sq2 += row[4 + k]; ssp += row[8 + k]; sp2 += row[12 + k];
        }
        statL[0][t] = ssq; statL[1][t] = sq2; statL[2][t] = ssp; statL[3][t] = sp2;
    }
    __syncthreads();
    #pragma unroll
    for (int j = 0; j < 4; ++j)
        stage[tr * 64 + m0 + j] = acc[0][j] + acc[1][j] + acc[2][j] + acc[3][j];
    __syncthreads();
    if (t < NN) {
        float cs = 0;
        #pragma unroll
        for (int i = 0; i < 16; ++i) cs += stage[i * 64 + t];
        float w2 = fmaxf(cs * (1.0f/64.0f), 0.0f) + 0.001f;
        float w1 = fmaxf(uL[t] * (1.0f/64.0f), 0.0f) + 0.001f;
        float s1 = w1, s2 = w2;
        #pragma unroll
        for (int m = 1; m < 64; m <<= 1) {
            s1 += __shfl_xor(s1, m, 64);
            s2 += __shfl_xor(s2, m, 64);
        }
        rL[t] = w1 / s1;
        cL[t] = w2 / s2;
        vL[t] = 1.0f;
    }
    __syncthreads();

    {
        float nq_[4], np_[4], sqn[4], spm[4];
        #pragma unroll
        for (int i = 0; i < 4; ++i) {
            float sv  = statL[0][n0 + i];
            float var = statL[1][n0 + i] - sv * sv * (1.0f/1024.0f);
            nq_[i] = fmaxf(sqrtf(fmaxf(var, 0.0f)), 1e-8f);
            sqn[i] = sv;
        }
        #pragma unroll
        for (int j = 0; j < 4; ++j) {
            float sv  = statL[2][m0 + j];
            float var = statL[3][m0 + j] - sv * sv * (1.0f/1024.0f);
            np_[j] = fmaxf(sqrtf(fmaxf(var, 0.0f)), 1e-8f);
            spm[j] = sv;
        }
        #pragma unroll
        for (int i = 0; i < 4; ++i) {
            #pragma unroll
            for (int j = 0; j < 4; ++j) {
                float sim = (acc[i][j] - sqn[i] * spm[j] * (1.0f/1024.0f)) / (nq_[i] * np_[j]);
                acc[i][j] = sim;
                float Kv = exp2f((sim - 1.0f) * KSC);
                Kl [n0 + i][m0 + j] = Kv;
                KTl[m0 + j][n0 + i] = Kv;
            }
        }
    }
    __syncthreads();

    const int sn  = t >> 2;
    const int sp4 = t & 3;
    float Kr[16], KTr[16];
    #pragma unroll
    for (int jj = 0; jj < 4; ++jj) {
        float4 kv = *(const float4*)&Kl [sn][sp4 * 16 + jj * 4];
        float4 kt = *(const float4*)&KTl[sn][sp4 * 16 + jj * 4];
        Kr [jj*4+0]=kv.x; Kr [jj*4+1]=kv.y; Kr [jj*4+2]=kv.z; Kr [jj*4+3]=kv.w;
        KTr[jj*4+0]=kt.x; KTr[jj*4+1]=kt.y; KTr[jj*4+2]=kt.z; KTr[jj*4+3]=kt.w;
    }
    const float rreg = rL[sn];
    const float creg = cL[sn];

    for (int it = 0; it < 100; ++it) {
        float s = DOT16(Kr, vL);
        s += __shfl_xor(s, 1, 64); s += __shfl_xor(s, 2, 64);
        float u = rreg / fmaxf(s, 1e-30f);
        if (sp4 == 0) uL[sn] = u;
        __syncthreads();
        float s2 = DOT16(KTr, uL);
        s2 += __shfl_xor(s2, 1, 64); s2 += __shfl_xor(s2, 2, 64);
        float vv = creg / fmaxf(s2, 1e-30f);
        if (sp4 == 0) vL[sn] = vv;
        __syncthreads();
    }
    {
        float s = DOT16(Kr, vL);
        s += __shfl_xor(s, 1, 64); s += __shfl_xor(s, 2, 64);
        float u = rreg / fmaxf(s, 1e-30f);
        if (sp4 == 0) uL[sn] = u;
    }
    __syncthreads();

    float uu[4], vv_[4];
    #pragma unroll
    for (int i = 0; i < 4; ++i) uu[i]  = uL[n0 + i];
    #pragma unroll
    for (int j = 0; j < 4; ++j) vv_[j] = vL[m0 + j];
    float part = 0.0f;
    #pragma unroll
    for (int i = 0; i < 4; ++i) {
        #pragma unroll
        for (int j = 0; j < 4; ++j) {
            float sim = acc[i][j];
            float Kv  = exp2f((sim - 1.0f) * KSC);
            part = fmaf(sim * Kv, uu[i] * vv_[j], part);
        }
    }
    #pragma unroll
    for (int m = 1; m < 64; m <<= 1) part += __shfl_xor(part, m, 64);
    if ((t & 63) == 0) redl[t >> 6] = part;
    __syncthreads();
    if (t == 0) out[b] = (redl[0] + redl[1] + redl[2] + redl[3]) * (12.5f / 64.0f);
}

extern "C" void kernel_launch(void* const* d_in, const int* in_sizes, int n_in,
                              void* d_out, int out_size, void* d_ws, size_t ws_size,
                              hipStream_t stream) {
    const float* proto = (const float*)d_in[0];
    const float* query = (const float*)d_in[1];
    float* out = (float*)d_out;
    (void)in_sizes; (void)n_in; (void)out_size;

    const size_t need = (size_t)512 * SPLIT * WSB * sizeof(float);   // ~35.7 MB
    if (ws_size >= need) {
        gram_w4  <<<dim3(512 * SPLIT), dim3(256), 0, stream>>>(proto, query, (float*)d_ws);
        emd_solve<<<dim3(512),         dim3(256), 0, stream>>>((const float*)d_ws, out);
    } else {
        deepemd_fused<<<dim3(512), dim3(256), 0, stream>>>(proto, query, out);
    }
}

// Round 11
// 120.217 us; speedup vs baseline: 3.3284x; 1.1269x over previous
//
#include <hip/hip_runtime.h>
#include <math.h>

#define NCH    1024
#define NN     64
#define CK     32                    // fused-fallback chunk
#define KSC    28.853900817779268f   // 20*log2(e): exp(-cost/0.05) = 2^((sim-1)*KSC)
#define SPLIT  4                     // records per batch in ws
#define WSB    4352                  // floats per record: 4096 gram + 4*64 stats

typedef __attribute__((ext_vector_type(8))) short bf16x8;
typedef __attribute__((ext_vector_type(4))) float f32x4;
typedef union { unsigned int u[4]; bf16x8 v; } FragCvt;

// stats accumulation from loaded registers (nodes 4*(l&15)+k of channel grp*4+(l>>4))
#define STAT_Q(v) { sqp[0]+=(v).x; q2p[0]=fmaf((v).x,(v).x,q2p[0]); \
                    sqp[1]+=(v).y; q2p[1]=fmaf((v).y,(v).y,q2p[1]); \
                    sqp[2]+=(v).z; q2p[2]=fmaf((v).z,(v).z,q2p[2]); \
                    sqp[3]+=(v).w; q2p[3]=fmaf((v).w,(v).w,q2p[3]); }
#define STAT_P(v) { spp[0]+=(v).x; p2p[0]=fmaf((v).x,(v).x,p2p[0]); \
                    spp[1]+=(v).y; p2p[1]=fmaf((v).y,(v).y,p2p[1]); \
                    spp[2]+=(v).z; p2p[2]=fmaf((v).z,(v).z,p2p[2]); \
                    spp[3]+=(v).w; p2p[3]=fmaf((v).w,(v).w,p2p[3]); }

// x -> hi (RNE bf16) + lo (trunc bf16); pack 2 elems into hi-dword / lo-dword.
// Error: |x - hi - lo| <= 2^-17|x|; dropping lo*lo in the Gram <= 2^-18|x||y|.
__device__ __forceinline__ void cvt2(float x0, float x1,
                                     unsigned int& hw, unsigned int& lw) {
    unsigned int u0 = __float_as_uint(x0), u1 = __float_as_uint(x1);
    unsigned int h0 = (u0 + 0x7FFFu + ((u0 >> 16) & 1u)) & 0xFFFF0000u;
    unsigned int h1 = (u1 + 0x7FFFu + ((u1 >> 16) & 1u)) & 0xFFFF0000u;
    hw = (h0 >> 16) | h1;
    float l0 = x0 - __uint_as_float(h0);
    float l1 = x1 - __uint_as_float(h1);
    lw = (__float_as_uint(l0) >> 16) | (__float_as_uint(l1) & 0xFFFF0000u);
}

// swizzled fp32 LDS element (k, n): layout [32 k][64 n], 256B per k-row,
// 16B slot index XOR'd by ((k>>3)&3)<<1 -> 2-way (free) on stores AND k-strided reads.
__device__ __forceinline__ float ldread(const char* base, int k, int n) {
    int off = (k << 8) + (((n >> 2) << 4) | ((n & 3) << 2));
    off ^= ((k >> 3) & 3) << 5;
    return *(const float*)(base + off);
}

// ===================== Kernel A: MFMA Gram partials =====================
// grid = 2048 blocks x 64 thr (1 wave = 1 ws record = 256 channels).
// Per 32-ch chunk: float4 global loads (R10 pattern) -> stats from regs ->
// swizzled fp32 LDS stage -> per-frag bf16 hi/lo split -> 3x mfma_16x16x32_bf16
// per 16x16 tile (hi*hi + hi*lo + lo*hi). No barriers anywhere.
__global__ __launch_bounds__(64)
void gram_mfma(const float* __restrict__ proto,
               const float* __restrict__ query,
               float* __restrict__ ws)
{
    __shared__ __align__(16) char ldsbuf[16384];   // Q fp32 8KB | P fp32 8KB
    char* const ldsQ = ldsbuf;
    char* const ldsP = ldsbuf + 8192;

    const int bid = blockIdx.x;          // 2048 records
    const int b = bid >> 2, s = bid & 3;
    const int l = threadIdx.x;           // 0..63
    const int lam = l & 15, g = l >> 4;

    const float* __restrict__ qw = query + (size_t)b * 65536 + s * 16384;
    const float* __restrict__ pw = proto + (size_t)b * 65536 + s * 16384;

    f32x4 acc[4][4];
    #pragma unroll
    for (int r = 0; r < 4; ++r)
        #pragma unroll
        for (int c = 0; c < 4; ++c) {
            acc[r][c][0] = 0.0f; acc[r][c][1] = 0.0f;
            acc[r][c][2] = 0.0f; acc[r][c][3] = 0.0f;
        }
    float sqp[4] = {0,0,0,0}, q2p[4] = {0,0,0,0};
    float spp[4] = {0,0,0,0}, p2p[4] = {0,0,0,0};

    #pragma unroll 1
    for (int ch8 = 0; ch8 < 8; ++ch8) {
        // ---- load 32 channels (16 float4/lane), stats, swizzled LDS stage ----
        float4 qv[8], pv[8];
        #pragma unroll
        for (int grp = 0; grp < 8; ++grp) {
            qv[grp] = *(const float4*)(qw + ch8 * 2048 + grp * 256 + 4 * l);
            pv[grp] = *(const float4*)(pw + ch8 * 2048 + grp * 256 + 4 * l);
        }
        #pragma unroll
        for (int grp = 0; grp < 8; ++grp) {
            STAT_Q(qv[grp]); STAT_P(pv[grp]);
            const int kk = grp * 4 + g;                 // chunk-local channel
            int off = (kk << 8) + (lam << 4);           // float4 = nodes 4lam..+3
            off ^= ((kk >> 3) & 3) << 5;
            *(float4*)(ldsQ + off) = qv[grp];
            *(float4*)(ldsP + off) = pv[grp];
        }
        // ---- B frags (p side): 4 col-tiles, k = 8g..8g+7 ----
        unsigned int bh[4][4], bl[4][4];
        #pragma unroll
        for (int c = 0; c < 4; ++c)
            #pragma unroll
            for (int d = 0; d < 4; ++d) {
                float x0 = ldread(ldsP, 8 * g + 2 * d,     c * 16 + lam);
                float x1 = ldread(ldsP, 8 * g + 2 * d + 1, c * 16 + lam);
                cvt2(x0, x1, bh[c][d], bl[c][d]);
            }
        // ---- A frags (q side) per row-tile + MFMAs ----
        #pragma unroll
        for (int r = 0; r < 4; ++r) {
            FragCvt ah, al;
            #pragma unroll
            for (int d = 0; d < 4; ++d) {
                float x0 = ldread(ldsQ, 8 * g + 2 * d,     r * 16 + lam);
                float x1 = ldread(ldsQ, 8 * g + 2 * d + 1, r * 16 + lam);
                cvt2(x0, x1, ah.u[d], al.u[d]);
            }
            #pragma unroll
            for (int c = 0; c < 4; ++c) {
                FragCvt bhv, blv;
                bhv.u[0] = bh[c][0]; bhv.u[1] = bh[c][1];
                bhv.u[2] = bh[c][2]; bhv.u[3] = bh[c][3];
                blv.u[0] = bl[c][0]; blv.u[1] = bl[c][1];
                blv.u[2] = bl[c][2]; blv.u[3] = bl[c][3];
                acc[r][c] = __builtin_amdgcn_mfma_f32_16x16x32_bf16(ah.v, bhv.v, acc[r][c], 0, 0, 0);
                acc[r][c] = __builtin_amdgcn_mfma_f32_16x16x32_bf16(ah.v, blv.v, acc[r][c], 0, 0, 0);
                acc[r][c] = __builtin_amdgcn_mfma_f32_16x16x32_bf16(al.v, bhv.v, acc[r][c], 0, 0, 0);
            }
        }
    }

    // ---- stats reduce: lanes l, l^16, l^32, l^48 cover disjoint channels ----
    #pragma unroll
    for (int k = 0; k < 4; ++k) {
        sqp[k] += __shfl_xor(sqp[k], 16, 64); sqp[k] += __shfl_xor(sqp[k], 32, 64);
        q2p[k] += __shfl_xor(q2p[k], 16, 64); q2p[k] += __shfl_xor(q2p[k], 32, 64);
        spp[k] += __shfl_xor(spp[k], 16, 64); spp[k] += __shfl_xor(spp[k], 32, 64);
        p2p[k] += __shfl_xor(p2p[k], 16, 64); p2p[k] += __shfl_xor(p2p[k], 32, 64);
    }

    // ---- write record: C layout row=(lane>>4)*4+reg, col=lane&15 (verified m89/m91) ----
    float* __restrict__ wsb = ws + (size_t)bid * WSB;
    #pragma unroll
    for (int r = 0; r < 4; ++r)
        #pragma unroll
        for (int c = 0; c < 4; ++c)
            #pragma unroll
            for (int i = 0; i < 4; ++i)
                wsb[(r * 16 + 4 * g + i) * 64 + c * 16 + lam] = acc[r][c][i];
    if (l < 16) {
        #pragma unroll
        for (int k = 0; k < 4; ++k) {
            wsb[4096 +   0 + 4 * lam + k] = sqp[k];
            wsb[4096 +  64 + 4 * lam + k] = q2p[k];
            wsb[4096 + 128 + 4 * lam + k] = spp[k];
            wsb[4096 + 192 + 4 * lam + k] = p2p[k];
        }
    }
}

#define DOT16(KK, ARR) ({ \
    float4 x0 = *(const float4*)&ARR[sp4*16 +  0]; \
    float4 x1 = *(const float4*)&ARR[sp4*16 +  4]; \
    float4 x2 = *(const float4*)&ARR[sp4*16 +  8]; \
    float4 x3 = *(const float4*)&ARR[sp4*16 + 12]; \
    float a0 = 0.0f, a1 = 0.0f; \
    a0=fmaf(KK[0],x0.x,a0);  a1=fmaf(KK[1],x0.y,a1); \
    a0=fmaf(KK[2],x0.z,a0);  a1=fmaf(KK[3],x0.w,a1); \
    a0=fmaf(KK[4],x1.x,a0);  a1=fmaf(KK[5],x1.y,a1); \
    a0=fmaf(KK[6],x1.z,a0);  a1=fmaf(KK[7],x1.w,a1); \
    a0=fmaf(KK[8],x2.x,a0);  a1=fmaf(KK[9],x2.y,a1); \
    a0=fmaf(KK[10],x2.z,a0); a1=fmaf(KK[11],x2.w,a1); \
    a0=fmaf(KK[12],x3.x,a0); a1=fmaf(KK[13],x3.y,a1); \
    a0=fmaf(KK[14],x3.z,a0); a1=fmaf(KK[15],x3.w,a1); \
    a0 + a1; })

// ===================== Kernel B: combine + sim + K + Sinkhorn + logits (verified R2/R3) =====================
__global__ __launch_bounds__(256)
void emd_solve(const float* __restrict__ ws, float* __restrict__ out)
{
    __shared__ __align__(16) float stage[16 * 64];
    __shared__ __align__(16) float Kl [NN][68];
    __shared__ __align__(16) float KTl[NN][68];
    __shared__ __align__(16) float statL[4][NN];
    __shared__ __align__(16) float uL[NN];
    __shared__ __align__(16) float vL[NN];
    __shared__ __align__(16) float rL[NN];
    __shared__ __align__(16) float cL[NN];
    __shared__ float redl[4];

    const int b  = blockIdx.x;
    const int t  = threadIdx.x;
    const int tr = t >> 4, tc = t & 15;
    const int n0 = tr * 4, m0 = tc * 4;

    const float* __restrict__ wsb = ws + (size_t)b * SPLIT * WSB;

    float acc[4][4];
    #pragma unroll
    for (int i = 0; i < 4; ++i)
        #pragma unroll
        for (int j = 0; j < 4; ++j) acc[i][j] = 0.0f;
    #pragma unroll
    for (int s = 0; s < SPLIT; ++s) {
        const float* __restrict__ g = wsb + s * WSB;
        #pragma unroll
        for (int i = 0; i < 4; ++i) {
            float4 v = *(const float4*)&g[(n0 + i) * 64 + m0];
            acc[i][0] += v.x; acc[i][1] += v.y; acc[i][2] += v.z; acc[i][3] += v.w;
        }
    }
    if (t < NN) {
        float s0 = 0, s1 = 0, s2 = 0, s3 = 0;
        #pragma unroll
        for (int s = 0; s < SPLIT; ++s) {
            const float* __restrict__ g = wsb + s * WSB + 4096;
            s0 += g[t]; s1 += g[64 + t]; s2 += g[128 + t]; s3 += g[192 + t];
        }
        statL[0][t] = s0; statL[1][t] = s1; statL[2][t] = s2; statL[3][t] = s3;
    }
    #pragma unroll
    for (int i = 0; i < 4; ++i) {
        float s = acc[i][0] + acc[i][1] + acc[i][2] + acc[i][3];
        s += __shfl_xor(s, 1, 64); s += __shfl_xor(s, 2, 64);
        s += __shfl_xor(s, 4, 64); s += __shfl_xor(s, 8, 64);
        if (tc == 0) uL[n0 + i] = s;
    }
    #pragma unroll
    for (int j = 0; j < 4; ++j)
        stage[tr * 64 + m0 + j] = acc[0][j] + acc[1][j] + acc[2][j] + acc[3][j];
    __syncthreads();

    if (t < NN) {
        float cs = 0;
        #pragma unroll
        for (int i = 0; i < 16; ++i) cs += stage[i * 64 + t];
        float w2 = fmaxf(cs * (1.0f/64.0f), 0.0f) + 0.001f;
        float w1 = fmaxf(uL[t] * (1.0f/64.0f), 0.0f) + 0.001f;
        float s1 = w1, s2 = w2;
        #pragma unroll
        for (int m = 1; m < 64; m <<= 1) {
            s1 += __shfl_xor(s1, m, 64);
            s2 += __shfl_xor(s2, m, 64);
        }
        rL[t] = w1 / s1;
        cL[t] = w2 / s2;
        vL[t] = 1.0f;
    }
    {
        float nq_[4], np_[4], sqn[4], spm[4];
        #pragma unroll
        for (int i = 0; i < 4; ++i) {
            float sv  = statL[0][n0 + i];
            float var = statL[1][n0 + i] - sv * sv * (1.0f/1024.0f);
            nq_[i] = fmaxf(sqrtf(fmaxf(var, 0.0f)), 1e-8f);
            sqn[i] = sv;
        }
        #pragma unroll
        for (int j = 0; j < 4; ++j) {
            float sv  = statL[2][m0 + j];
            float var = statL[3][m0 + j] - sv * sv * (1.0f/1024.0f);
            np_[j] = fmaxf(sqrtf(fmaxf(var, 0.0f)), 1e-8f);
            spm[j] = sv;
        }
        #pragma unroll
        for (int i = 0; i < 4; ++i) {
            #pragma unroll
            for (int j = 0; j < 4; ++j) {
                float sim = (acc[i][j] - sqn[i] * spm[j] * (1.0f/1024.0f)) / (nq_[i] * np_[j]);
                acc[i][j] = sim;
                float Kv = exp2f((sim - 1.0f) * KSC);
                Kl [n0 + i][m0 + j] = Kv;
                KTl[m0 + j][n0 + i] = Kv;
            }
        }
    }
    __syncthreads();

    const int sn  = t >> 2;
    const int sp4 = t & 3;
    float Kr[16], KTr[16];
    #pragma unroll
    for (int jj = 0; jj < 4; ++jj) {
        float4 kv = *(const float4*)&Kl [sn][sp4 * 16 + jj * 4];
        float4 kt = *(const float4*)&KTl[sn][sp4 * 16 + jj * 4];
        Kr [jj*4+0]=kv.x; Kr [jj*4+1]=kv.y; Kr [jj*4+2]=kv.z; Kr [jj*4+3]=kv.w;
        KTr[jj*4+0]=kt.x; KTr[jj*4+1]=kt.y; KTr[jj*4+2]=kt.z; KTr[jj*4+3]=kt.w;
    }
    const float rreg = rL[sn];
    const float creg = cL[sn];

    for (int it = 0; it < 100; ++it) {
        float s = DOT16(Kr, vL);
        s += __shfl_xor(s, 1, 64); s += __shfl_xor(s, 2, 64);
        float u = rreg / fmaxf(s, 1e-30f);
        if (sp4 == 0) uL[sn] = u;
        __syncthreads();
        float s2 = DOT16(KTr, uL);
        s2 += __shfl_xor(s2, 1, 64); s2 += __shfl_xor(s2, 2, 64);
        float vv = creg / fmaxf(s2, 1e-30f);
        if (sp4 == 0) vL[sn] = vv;
        __syncthreads();
    }
    {
        float s = DOT16(Kr, vL);
        s += __shfl_xor(s, 1, 64); s += __shfl_xor(s, 2, 64);
        float u = rreg / fmaxf(s, 1e-30f);
        if (sp4 == 0) uL[sn] = u;
    }
    __syncthreads();

    float uu[4], vv_[4];
    #pragma unroll
    for (int i = 0; i < 4; ++i) uu[i]  = uL[n0 + i];
    #pragma unroll
    for (int j = 0; j < 4; ++j) vv_[j] = vL[m0 + j];
    float part = 0.0f;
    #pragma unroll
    for (int i = 0; i < 4; ++i) {
        #pragma unroll
        for (int j = 0; j < 4; ++j) {
            float sim = acc[i][j];
            float Kv  = exp2f((sim - 1.0f) * KSC);
            part = fmaf(sim * Kv, uu[i] * vv_[j], part);
        }
    }
    #pragma unroll
    for (int m = 1; m < 64; m <<= 1) part += __shfl_xor(part, m, 64);
    if ((t & 63) == 0) redl[t >> 6] = part;
    __syncthreads();
    if (t == 0) out[b] = (redl[0] + redl[1] + redl[2] + redl[3]) * (12.5f / 64.0f);
}

// ===================== Fallback: verified fused single-kernel path =====================
#define STAT_QF(v) { sqp[0]+=(v).x; q2p[0]=fmaf((v).x,(v).x,q2p[0]); \
                     sqp[1]+=(v).y; q2p[1]=fmaf((v).y,(v).y,q2p[1]); \
                     sqp[2]+=(v).z; q2p[2]=fmaf((v).z,(v).z,q2p[2]); \
                     sqp[3]+=(v).w; q2p[3]=fmaf((v).w,(v).w,q2p[3]); }
#define STAT_PF(v) { spp[0]+=(v).x; p2p[0]=fmaf((v).x,(v).x,p2p[0]); \
                     spp[1]+=(v).y; p2p[1]=fmaf((v).y,(v).y,p2p[1]); \
                     spp[2]+=(v).z; p2p[2]=fmaf((v).z,(v).z,p2p[2]); \
                     spp[3]+=(v).w; p2p[3]=fmaf((v).w,(v).w,p2p[3]); }

__global__ __launch_bounds__(256)
void deepemd_fused(const float* __restrict__ proto,
                   const float* __restrict__ query,
                   float* __restrict__ out)
{
    __shared__ __align__(16) float stage[2 * CK * NN];
    __shared__ __align__(16) float Kl [NN][68];
    __shared__ __align__(16) float KTl[NN][68];
    __shared__ __align__(16) float statL[4][NN];
    __shared__ __align__(16) float uL[NN];
    __shared__ __align__(16) float vL[NN];
    __shared__ __align__(16) float rL[NN];
    __shared__ __align__(16) float cL[NN];
    __shared__ float redl[4];

    const int b  = blockIdx.x;
    const int t  = threadIdx.x;
    const int tr = t >> 4, tc = t & 15;
    const int n0 = tr * 4, m0 = tc * 4;
    const int ofs = 4 * t;

    const float* __restrict__ pb = proto + (size_t)b * (NCH * NN);
    const float* __restrict__ qb = query + (size_t)b * (NCH * NN);

    float acc[4][4];
    #pragma unroll
    for (int i = 0; i < 4; ++i)
        #pragma unroll
        for (int j = 0; j < 4; ++j) acc[i][j] = 0.0f;
    float sqp[4] = {0,0,0,0}, q2p[4] = {0,0,0,0};
    float spp[4] = {0,0,0,0}, p2p[4] = {0,0,0,0};

    float4 qv0 = *(const float4*)(qb + ofs);
    float4 qv1 = *(const float4*)(qb + 1024 + ofs);
    float4 pv0 = *(const float4*)(pb + ofs);
    float4 pv1 = *(const float4*)(pb + 1024 + ofs);

    for (int ch = 0; ch < NCH / CK; ++ch) {
        if (ch) __syncthreads();
        *(float4*)&stage[       ofs] = qv0;
        *(float4*)&stage[1024 + ofs] = qv1;
        *(float4*)&stage[2048 + ofs] = pv0;
        *(float4*)&stage[3072 + ofs] = pv1;
        float4 nq0, nq1, np0, np1;
        const bool more = (ch + 1 < NCH / CK);
        if (more) {
            const float* qn = qb + (ch + 1) * 2048;
            const float* pn = pb + (ch + 1) * 2048;
            nq0 = *(const float4*)(qn + ofs);
            nq1 = *(const float4*)(qn + 1024 + ofs);
            np0 = *(const float4*)(pn + ofs);
            np1 = *(const float4*)(pn + 1024 + ofs);
        }
        STAT_QF(qv0); STAT_QF(qv1);
        STAT_PF(pv0); STAT_PF(pv1);
        __syncthreads();
        #pragma unroll 8
        for (int cc = 0; cc < CK; ++cc) {
            float4 a  = *(const float4*)&stage[cc * 64 + n0];
            float4 bb = *(const float4*)&stage[2048 + cc * 64 + m0];
            acc[0][0]=fmaf(a.x,bb.x,acc[0][0]); acc[0][1]=fmaf(a.x,bb.y,acc[0][1]);
            acc[0][2]=fmaf(a.x,bb.z,acc[0][2]); acc[0][3]=fmaf(a.x,bb.w,acc[0][3]);
            acc[1][0]=fmaf(a.y,bb.x,acc[1][0]); acc[1][1]=fmaf(a.y,bb.y,acc[1][1]);
            acc[1][2]=fmaf(a.y,bb.z,acc[1][2]); acc[1][3]=fmaf(a.y,bb.w,acc[1][3]);
            acc[2][0]=fmaf(a.z,bb.x,acc[2][0]); acc[2][1]=fmaf(a.z,bb.y,acc[2][1]);
            acc[2][2]=fmaf(a.z,bb.z,acc[2][2]); acc[2][3]=fmaf(a.z,bb.w,acc[2][3]);
            acc[3][0]=fmaf(a.w,bb.x,acc[3][0]); acc[3][1]=fmaf(a.w,bb.y,acc[3][1]);
            acc[3][2]=fmaf(a.w,bb.z,acc[3][2]); acc[3][3]=fmaf(a.w,bb.w,acc[3][3]);
        }
        if (more) { qv0 = nq0; qv1 = nq1; pv0 = np0; pv1 = np1; }
    }
    __syncthreads();

    #pragma unroll
    for (int i = 0; i < 4; ++i) {
        float s = acc[i][0] + acc[i][1] + acc[i][2] + acc[i][3];
        s += __shfl_xor(s, 1, 64); s += __shfl_xor(s, 2, 64);
        s += __shfl_xor(s, 4, 64); s += __shfl_xor(s, 8, 64);
        if (tc == 0) uL[n0 + i] = s;
    }
    #pragma unroll
    for (int k = 0; k < 4; ++k) {
        stage[t*16 +      k] = sqp[k];
        stage[t*16 +  4 + k] = q2p[k];
        stage[t*16 +  8 + k] = spp[k];
        stage[t*16 + 12 + k] = p2p[k];
    }
    __syncthreads();
    if (t < NN) {
        const int g = t >> 2, k = t & 3;
        float ssq = 0, sq2 = 0, ssp = 0, sp2 = 0;
        #pragma unroll
        for (int j = 0; j < 16; ++j) {
            const float* row = &stage[(j * 16 + g) * 16];
            ssq += row[k]; sq2 += row[4 + k]; ssp += row[8 + k]; sp2 += row[12 + k];
        }
        statL[0][t] = ssq; statL[1][t] = sq2; statL[2][t] = ssp; statL[3][t] = sp2;
    }
    __syncthreads();
    #pragma unroll
    for (int j = 0; j < 4; ++j)
        stage[tr * 64 + m0 + j] = acc[0][j] + acc[1][j] + acc[2][j] + acc[3][j];
    __syncthreads();
    if (t < NN) {
        float cs = 0;
        #pragma unroll
        for (int i = 0; i < 16; ++i) cs += stage[i * 64 + t];
        float w2 = fmaxf(cs * (1.0f/64.0f), 0.0f) + 0.001f;
        float w1 = fmaxf(uL[t] * (1.0f/64.0f), 0.0f) + 0.001f;
        float s1 = w1, s2 = w2;
        #pragma unroll
        for (int m = 1; m < 64; m <<= 1) {
            s1 += __shfl_xor(s1, m, 64);
            s2 += __shfl_xor(s2, m, 64);
        }
        rL[t] = w1 / s1;
        cL[t] = w2 / s2;
        vL[t] = 1.0f;
    }
    __syncthreads();

    {
        float nq_[4], np_[4], sqn[4], spm[4];
        #pragma unroll
        for (int i = 0; i < 4; ++i) {
            float sv  = statL[0][n0 + i];
            float var = statL[1][n0 + i] - sv * sv * (1.0f/1024.0f);
            nq_[i] = fmaxf(sqrtf(fmaxf(var, 0.0f)), 1e-8f);
            sqn[i] = sv;
        }
        #pragma unroll
        for (int j = 0; j < 4; ++j) {
            float sv  = statL[2][m0 + j];
            float var = statL[3][m0 + j] - sv * sv * (1.0f/1024.0f);
            np_[j] = fmaxf(sqrtf(fmaxf(var, 0.0f)), 1e-8f);
            spm[j] = sv;
        }
        #pragma unroll
        for (int i = 0; i < 4; ++i) {
            #pragma unroll
            for (int j = 0; j < 4; ++j) {
                float sim = (acc[i][j] - sqn[i] * spm[j] * (1.0f/1024.0f)) / (nq_[i] * np_[j]);
                acc[i][j] = sim;
                float Kv = exp2f((sim - 1.0f) * KSC);
                Kl [n0 + i][m0 + j] = Kv;
                KTl[m0 + j][n0 + i] = Kv;
            }
        }
    }
    __syncthreads();

    const int sn  = t >> 2;
    const int sp4 = t & 3;
    float Kr[16], KTr[16];
    #pragma unroll
    for (int jj = 0; jj < 4; ++jj) {
        float4 kv = *(const float4*)&Kl [sn][sp4 * 16 + jj * 4];
        float4 kt = *(const float4*)&KTl[sn][sp4 * 16 + jj * 4];
        Kr [jj*4+0]=kv.x; Kr [jj*4+1]=kv.y; Kr [jj*4+2]=kv.z; Kr [jj*4+3]=kv.w;
        KTr[jj*4+0]=kt.x; KTr[jj*4+1]=kt.y; KTr[jj*4+2]=kt.z; KTr[jj*4+3]=kt.w;
    }
    const float rreg = rL[sn];
    const float creg = cL[sn];

    for (int it = 0; it < 100; ++it) {
        float s = DOT16(Kr, vL);
        s += __shfl_xor(s, 1, 64); s += __shfl_xor(s, 2, 64);
        float u = rreg / fmaxf(s, 1e-30f);
        if (sp4 == 0) uL[sn] = u;
        __syncthreads();
        float s2 = DOT16(KTr, uL);
        s2 += __shfl_xor(s2, 1, 64); s2 += __shfl_xor(s2, 2, 64);
        float vv = creg / fmaxf(s2, 1e-30f);
        if (sp4 == 0) vL[sn] = vv;
        __syncthreads();
    }
    {
        float s = DOT16(Kr, vL);
        s += __shfl_xor(s, 1, 64); s += __shfl_xor(s, 2, 64);
        float u = rreg / fmaxf(s, 1e-30f);
        if (sp4 == 0) uL[sn] = u;
    }
    __syncthreads();

    float uu[4], vv_[4];
    #pragma unroll
    for (int i = 0; i < 4; ++i) uu[i]  = uL[n0 + i];
    #pragma unroll
    for (int j = 0; j < 4; ++j) vv_[j] = vL[m0 + j];
    float part = 0.0f;
    #pragma unroll
    for (int i = 0; i < 4; ++i) {
        #pragma unroll
        for (int j = 0; j < 4; ++j) {
            float sim = acc[i][j];
            float Kv  = exp2f((sim - 1.0f) * KSC);
            part = fmaf(sim * Kv, uu[i] * vv_[j], part);
        }
    }
    #pragma unroll
    for (int m = 1; m < 64; m <<= 1) part += __shfl_xor(part, m, 64);
    if ((t & 63) == 0) redl[t >> 6] = part;
    __syncthreads();
    if (t == 0) out[b] = (redl[0] + redl[1] + redl[2] + redl[3]) * (12.5f / 64.0f);
}

extern "C" void kernel_launch(void* const* d_in, const int* in_sizes, int n_in,
                              void* d_out, int out_size, void* d_ws, size_t ws_size,
                              hipStream_t stream) {
    const float* proto = (const float*)d_in[0];
    const float* query = (const float*)d_in[1];
    float* out = (float*)d_out;
    (void)in_sizes; (void)n_in; (void)out_size;

    const size_t need = (size_t)512 * SPLIT * WSB * sizeof(float);   // ~35.7 MB
    if (ws_size >= need) {
        gram_mfma<<<dim3(512 * SPLIT), dim3(64), 0, stream>>>(proto, query, (float*)d_ws);
        emd_solve<<<dim3(512),         dim3(256), 0, stream>>>((const float*)d_ws, out);
    } else {
        deepemd_fused<<<dim3(512), dim3(256), 0, stream>>>(proto, query, out);
    }
}